// Round 5
// baseline (27705.676 us; speedup 1.0000x reference)
//
#include <hip/hip_runtime.h>
#include <float.h>
#include <math.h>

#define N 8192
#define D 512
#define NB 16
#define EPSF 1e-8f

typedef _Float16 f16;
typedef __attribute__((ext_vector_type(4))) _Float16 f16x4v;
typedef __attribute__((ext_vector_type(8))) _Float16 f16x8v;
typedef __attribute__((ext_vector_type(4))) float f32x4v;

__device__ __forceinline__ bool lessp(float v1, int i1, float v2, int i2) {
  return (v1 < v2) || (v1 == v2 && i1 < i2);
}

__device__ __forceinline__ void gld16(const void* g, void* l) {
  __builtin_amdgcn_global_load_lds((const __attribute__((address_space(1))) void*)g,
                                   (__attribute__((address_space(3))) void*)l, 16, 0, 0);
}

// ---------------- kernel 1: z = mean over batch — np-exact: serial over b (axis-0
// reduce is serial elementwise adds in numpy), f32, then *1/16 (exact). + f16 split.
__global__ __launch_bounds__(256) void k_mean_split(const float* __restrict__ x, float* __restrict__ z,
                                                    f16* __restrict__ zhi, f16* __restrict__ zlo) {
  size_t i = (size_t)blockIdx.x * blockDim.x + threadIdx.x;  // float4 index
  const float4* x4 = (const float4*)x;
  float4 acc = x4[i];
#pragma unroll
  for (int b = 1; b < NB; ++b) {
    float4 v = x4[(size_t)b * (N * D / 4) + i];
    acc.x = __fadd_rn(acc.x, v.x); acc.y = __fadd_rn(acc.y, v.y);
    acc.z = __fadd_rn(acc.z, v.z); acc.w = __fadd_rn(acc.w, v.w);
  }
  const float s = 1.0f / NB;   // *0.0625 exact
  acc.x *= s; acc.y *= s; acc.z *= s; acc.w *= s;
  ((float4*)z)[i] = acc;
  float a[4] = {acc.x, acc.y, acc.z, acc.w};
  f16x4v h, l;
#pragma unroll
  for (int t = 0; t < 4; ++t) {
    f16 hh = (f16)a[t];
    h[t] = hh;
    l[t] = (f16)((a[t] - (float)hh) * 2048.0f);
  }
  ((f16x4v*)zhi)[i] = h;
  ((f16x4v*)zlo)[i] = l;
}

// ---------------- kernel 1b: sqnp_i = np.sum(z*z, -1) with numpy pairwise semantics ----
__device__ __forceinline__ float np_b128(const float* a) {
  float r[8];
#pragma unroll
  for (int j = 0; j < 8; ++j) r[j] = __fmul_rn(a[j], a[j]);
  for (int i = 8; i < 128; i += 8) {
#pragma unroll
    for (int j = 0; j < 8; ++j) r[j] = __fadd_rn(r[j], __fmul_rn(a[i + j], a[i + j]));
  }
  return __fadd_rn(__fadd_rn(__fadd_rn(r[0], r[1]), __fadd_rn(r[2], r[3])),
                   __fadd_rn(__fadd_rn(r[4], r[5]), __fadd_rn(r[6], r[7])));
}

__global__ __launch_bounds__(256) void k_sqnp(const float* __restrict__ z, float* __restrict__ sqnp) {
  int i = blockIdx.x * 256 + threadIdx.x;
  const float* a = &z[(size_t)i * D];
  // numpy pairwise n=512: (T128(0)+T128(128)) + (T128(256)+T128(384))
  float s0 = __fadd_rn(np_b128(a), np_b128(a + 128));
  float s1 = __fadd_rn(np_b128(a + 256), np_b128(a + 384));
  sqnp[i] = __fadd_rn(s0, s1);
}

// ---------------- kernel 2: column sums (for mean m) ----------------
__global__ __launch_bounds__(256) void k_colmean(const float* __restrict__ z, float* __restrict__ m) {
  int c = blockIdx.x * 256 + threadIdx.x;  // 0..511
  int r0 = blockIdx.y * 256;
  float acc = 0.f;
  for (int r = 0; r < 256; ++r) acc += z[(size_t)(r0 + r) * D + c];
  atomicAdd(&m[c], acc);
}

// ---------------- kernel 3: finalize m (mean), mm = <m,m> ----------------
__global__ void k_mm(float* __restrict__ m, float* __restrict__ scal) {
  __shared__ float red[512];
  int t = threadIdx.x;
  float v = m[t] * (1.0f / N);
  m[t] = v;
  red[t] = v * v;
  __syncthreads();
  for (int s = 256; s > 0; s >>= 1) {
    if (t < s) red[t] += red[t + s];
    __syncthreads();
  }
  if (t == 0) scal[0] = red[0];
}

// ---------------- kernel 4: per-row sq_i = |z_i|^2 (fast), p_i = <z_i, m> ----------------
__global__ __launch_bounds__(256) void k_rowstats(const float* __restrict__ z, const float* __restrict__ m,
                                                  float* __restrict__ sq, float* __restrict__ p) {
  int wave = threadIdx.x >> 6, lane = threadIdx.x & 63;
  int i = blockIdx.x * 4 + wave;
  const float4* zr = (const float4*)&z[(size_t)i * D];
  const float4* m4 = (const float4*)m;
  float asq = 0.f, ap = 0.f;
#pragma unroll
  for (int h = 0; h < 2; ++h) {
    int c4 = lane + h * 64;
    float4 v = zr[c4];
    float4 mv = m4[c4];
    asq += v.x * v.x + v.y * v.y + v.z * v.z + v.w * v.w;
    ap  += v.x * mv.x + v.y * mv.y + v.z * mv.z + v.w * mv.w;
  }
#pragma unroll
  for (int o = 32; o > 0; o >>= 1) {
    asq += __shfl_xor(asq, o);
    ap  += __shfl_xor(ap, o);
  }
  if (lane == 0) { sq[i] = asq; p[i] = ap; }
}

// ---------------- kernel 5: G = z z^T via f16-split MFMA (3 products) ----------------
// G = hi*hi + (hi*lo + lo*hi)/2048, fp32 accumulate. Only CKA consumes G values
// directly (insensitive, squashed by invf ~8.4e-5); knn uses G only for CANDIDATES.
__global__ __launch_bounds__(512, 2) void k_gemm(const f16* __restrict__ zhi, const f16* __restrict__ zlo,
                                                 float* __restrict__ G) {
  __shared__ __align__(16) f16 Ah[128 * 32], Al[128 * 32], Bh[128 * 32], Bl[128 * 32];  // 8 KB each
  const int tid = threadIdx.x;
  const int lane = tid & 63;
  const int w = tid >> 6;                 // 8 waves
  const int wm = w >> 2, wn = w & 3;      // 2 (M) x 4 (N)
  const int nwg = gridDim.x;              // 4096
  const int bid = blockIdx.x;
  const int swz = (bid & 7) * (nwg >> 3) + (bid >> 3);   // XCD-contiguous bands
  const int bx = swz & (N / 128 - 1);
  const int by = swz >> 6;
  const int r0 = by * 128, c0 = bx * 128;

  f32x4v acc1[4][2], acc2[4][2];
#pragma unroll
  for (int a = 0; a < 4; ++a)
#pragma unroll
    for (int b = 0; b < 2; ++b) {
      acc1[a][b] = (f32x4v){0.f, 0.f, 0.f, 0.f};
      acc2[a][b] = (f32x4v){0.f, 0.f, 0.f, 0.f};
    }

  // staging: thread stages 16B at LDS byte offset tid*16 (row tid>>2, slot tid&3).
  // LDS[row][t] holds global slot t ^ f(row), f(row) = (row>>1)&3  (bank de-conflict).
  const int srow = tid >> 2;                          // 0..127
  const int sslot = (tid & 3) ^ ((srow >> 1) & 3);
  const size_t abase = (size_t)(r0 + srow) * D + sslot * 8;
  const size_t bbase = (size_t)(c0 + srow) * D + sslot * 8;
  f16* lAh = &Ah[tid * 8];   // tid*16 bytes
  f16* lAl = &Al[tid * 8];
  f16* lBh = &Bh[tid * 8];
  f16* lBl = &Bl[tid * 8];

  const int s = lane >> 4;                // k-slab 0..3
  const int fr = lane & 15;               // fragment row/col lane part

  for (int kb = 0; kb < D; kb += 32) {
    __syncthreads();   // previous iter's reads done before overwrite
    gld16(zhi + abase + kb, lAh);
    gld16(zlo + abase + kb, lAl);
    gld16(zhi + bbase + kb, lBh);
    gld16(zlo + bbase + kb, lBl);
    __syncthreads();   // drains vmcnt(0): tiles visible

    f16x8v ah[4], al[4], bh[2], bl[2];
#pragma unroll
    for (int mi = 0; mi < 4; ++mi) {
      int m = wm * 64 + mi * 16 + fr;
      int off = m * 32 + ((s ^ ((m >> 1) & 3)) * 8);  // f16 elements
      ah[mi] = *(const f16x8v*)&Ah[off];
      al[mi] = *(const f16x8v*)&Al[off];
    }
#pragma unroll
    for (int ni = 0; ni < 2; ++ni) {
      int n = wn * 32 + ni * 16 + fr;
      int off = n * 32 + ((s ^ ((n >> 1) & 3)) * 8);
      bh[ni] = *(const f16x8v*)&Bh[off];
      bl[ni] = *(const f16x8v*)&Bl[off];
    }
#pragma unroll
    for (int mi = 0; mi < 4; ++mi)
#pragma unroll
      for (int ni = 0; ni < 2; ++ni) {
        acc1[mi][ni] = __builtin_amdgcn_mfma_f32_16x16x32_f16(ah[mi], bh[ni], acc1[mi][ni], 0, 0, 0);
        acc2[mi][ni] = __builtin_amdgcn_mfma_f32_16x16x32_f16(ah[mi], bl[ni], acc2[mi][ni], 0, 0, 0);
        acc2[mi][ni] = __builtin_amdgcn_mfma_f32_16x16x32_f16(al[mi], bh[ni], acc2[mi][ni], 0, 0, 0);
      }
  }

  const float sc = 1.0f / 2048.0f;
#pragma unroll
  for (int mi = 0; mi < 4; ++mi) {
    int row = r0 + wm * 64 + mi * 16 + s * 4;   // C/D: col=lane&15, row=(lane>>4)*4+reg
#pragma unroll
    for (int ni = 0; ni < 2; ++ni) {
      int col = c0 + wn * 32 + ni * 16 + fr;
#pragma unroll
      for (int r = 0; r < 4; ++r)
        G[(size_t)(row + r) * N + col] = acc1[mi][ni][r] + acc2[mi][ni][r] * sc;
    }
  }
}

// ---------------- top-16 helpers ----------------
__device__ __forceinline__ void ins16(float kv[16], int ki[16], float v, int j) {
  if (lessp(v, j, kv[15], ki[15])) {
    kv[15] = v; ki[15] = j;
#pragma unroll
    for (int t = 15; t > 0; --t) {
      if (lessp(kv[t], ki[t], kv[t - 1], ki[t - 1])) {
        float tv = kv[t]; kv[t] = kv[t - 1]; kv[t - 1] = tv;
        int ti = ki[t]; ki[t] = ki[t - 1]; ki[t - 1] = ti;
      }
    }
  }
}

__device__ __forceinline__ void merge16_shfl(float kv[16], int ki[16], int mask) {
  float mv[32]; int mi[32];
#pragma unroll
  for (int t = 0; t < 16; ++t) {
    mv[t] = kv[t]; mi[t] = ki[t];
    mv[31 - t] = __shfl_xor(kv[t], mask);   // reversed partner -> bitonic 32
    mi[31 - t] = __shfl_xor(ki[t], mask);
  }
#pragma unroll
  for (int d = 16; d >= 1; d >>= 1) {
#pragma unroll
    for (int s = 0; s < 32; ++s) {
      if ((s & d) == 0) {
        int u = s + d;
        if (lessp(mv[u], mi[u], mv[s], mi[s])) {
          float tv = mv[s]; mv[s] = mv[u]; mv[u] = tv;
          int ti = mi[s]; mi[s] = mi[u]; mi[u] = ti;
        }
      }
    }
  }
#pragma unroll
  for (int t = 0; t < 16; ++t) { kv[t] = mv[t]; ki[t] = mi[t]; }
}

// ---------------- kernel 6: pass2 — rs_i, fro partials, knn top-16 CANDIDATES ----------------
__global__ __launch_bounds__(256) void k_pass2(const float* __restrict__ G, const float* __restrict__ sq,
                                               const float* __restrict__ p, const float* __restrict__ scal,
                                               float* __restrict__ rs, float* __restrict__ fr,
                                               int* __restrict__ cand) {
  int wave = threadIdx.x >> 6, lane = threadIdx.x & 63;
  int i = blockIdx.x * 4 + wave;
  float mm = scal[0];
  float pi = p[i], sqi = sq[i];
  const float* Gr = &G[(size_t)i * N];
  float kv[16]; int ki[16];
#pragma unroll
  for (int t = 0; t < 16; ++t) { kv[t] = FLT_MAX; ki[t] = 0x7fffffff; }
  float fsum = 0.f, rsum = 0.f;
  for (int it = 0; it < N / 256; ++it) {
    int j0 = it * 256 + lane * 4;
    float4 g  = *(const float4*)&Gr[j0];
    float4 pj = *(const float4*)&p[j0];
    float4 sj = *(const float4*)&sq[j0];
    float kc, key;
    kc = g.x - pi - pj.x + mm; fsum += kc * kc; rsum += kc;
    key = fmaxf(sqi + sj.x - 2.f * g.x, 0.f); ins16(kv, ki, key, j0 + 0);
    kc = g.y - pi - pj.y + mm; fsum += kc * kc; rsum += kc;
    key = fmaxf(sqi + sj.y - 2.f * g.y, 0.f); ins16(kv, ki, key, j0 + 1);
    kc = g.z - pi - pj.z + mm; fsum += kc * kc; rsum += kc;
    key = fmaxf(sqi + sj.z - 2.f * g.z, 0.f); ins16(kv, ki, key, j0 + 2);
    kc = g.w - pi - pj.w + mm; fsum += kc * kc; rsum += kc;
    key = fmaxf(sqi + sj.w - 2.f * g.w, 0.f); ins16(kv, ki, key, j0 + 3);
  }
#pragma unroll
  for (int o = 1; o < 64; o <<= 1) merge16_shfl(kv, ki, o);
#pragma unroll
  for (int o = 32; o > 0; o >>= 1) {
    fsum += __shfl_xor(fsum, o);
    rsum += __shfl_xor(rsum, o);
  }
  if (lane == 0) {
    fr[i] = fsum; rs[i] = rsum;
#pragma unroll
    for (int t = 0; t < 16; ++t) cand[i * 16 + t] = ki[t];
  }
}

// ---------------- kernel 6b: refine — np-f32-mimic d on 16 candidates, true top-8 ----------------
// Reproduces: G=serial-k f32 FMA (BLAS micro-kernel order); d2 = fl(fl(sq_i+sq_j)-fl(2G));
// d = f32(sqrt(max(d2,0))); top-8 by (d, idx) lex (jax top_k index tie-break).
__global__ __launch_bounds__(256) void k_refine(const float* __restrict__ z, const float* __restrict__ sqnp,
                                                const int* __restrict__ cand, int* __restrict__ knn8) {
  __shared__ float dls[16][17];
  __shared__ int   jls[16][17];
  int tid = threadIdx.x;
  int r = tid >> 4;          // local row 0..15
  int c = tid & 15;          // candidate 0..15
  int i = blockIdx.x * 16 + r;
  int j = cand[i * 16 + c];
  const float* zi = &z[(size_t)i * D];
  const float* zj = &z[(size_t)j * D];
  float g = 0.f;
  for (int k = 0; k < D; ++k) g = fmaf(zi[k], zj[k], g);   // serial k ascending
  float t1 = __fadd_rn(sqnp[i], sqnp[j]);
  float d2 = __fsub_rn(t1, __fmul_rn(2.0f, g));
  float dd = (float)sqrt((double)fmaxf(d2, 0.f));
  dls[r][c] = dd; jls[r][c] = j;
  __syncthreads();
  if (c == 0) {
    for (int s = 0; s < 8; ++s) {
      int best = s;
      for (int t = s + 1; t < 16; ++t) {
        bool lt = (dls[r][t] < dls[r][best]) ||
                  (dls[r][t] == dls[r][best] && jls[r][t] < jls[r][best]);
        if (lt) best = t;
      }
      float td = dls[r][s]; dls[r][s] = dls[r][best]; dls[r][best] = td;
      int tj = jls[r][s]; jls[r][s] = jls[r][best]; jls[r][best] = tj;
      knn8[i * 8 + s] = jls[r][s];
    }
  }
}

// ---------------- kernel 7: reduce fro, sum(rs) ----------------
__global__ void k_reduce(const float* __restrict__ fr, const float* __restrict__ rs,
                         float* __restrict__ scal) {
  __shared__ float r1[1024], r2[1024];
  int t = threadIdx.x;
  float a = 0.f, b = 0.f;
  for (int i = t; i < N; i += 1024) { a += fr[i]; b += rs[i]; }
  r1[t] = a; r2[t] = b;
  __syncthreads();
  for (int s = 512; s > 0; s >>= 1) {
    if (t < s) { r1[t] += r1[t + s]; r2[t] += r2[t + s]; }
    __syncthreads();
  }
  if (t == 0) { scal[1] = sqrtf(r1[0]); scal[2] = r2[0]; }
}

// ---------------- kernel 8: q_j = (p_j + rs_j/N) * invf ----------------
__global__ __launch_bounds__(256) void k_prepq(const float* __restrict__ p, const float* __restrict__ rs,
                                               const float* __restrict__ scal, float* __restrict__ q) {
  int j = blockIdx.x * 256 + threadIdx.x;
  float invf = 1.0f / (scal[1] + EPSF);
  q[j] = (p[j] + rs[j] * (1.0f / N)) * invf;
}

// ---------------- kernel 9: fused pass3+pass4 — l1/s3 in-block, final A row ----------------
__global__ __launch_bounds__(256) void k_pass4(float* __restrict__ G, const float* __restrict__ q,
                                               const float* __restrict__ scal,
                                               const int* __restrict__ knn8) {
  __shared__ float row[N];        // 32 KB (k3 values, then A values)
  __shared__ float red1[256], red2[256];
  __shared__ int kidx[8];
  int i = blockIdx.x;
  int t = threadIdx.x;
  float invf = 1.0f / (scal[1] + EPSF);
  float cmean = scal[2] * invf / ((float)N * (float)N);
  float c0 = scal[0] * invf - q[i] + cmean;
  if (t < 8) kidx[t] = knn8[i * 8 + t];
  float* Gr = &G[(size_t)i * N];

  // sweep 1: k3 into LDS, accumulate l1 (sum |k3|) and s3 (sum k3)
  float al = 0.f, as = 0.f;
  for (int it = 0; it < N / 1024; ++it) {
    int j0 = it * 1024 + t * 4;
    float4 g  = *(const float4*)&Gr[j0];
    float4 qj = *(const float4*)&q[j0];
    float4 k3v;
    k3v.x = g.x * invf - qj.x + c0; al += fabsf(k3v.x); as += k3v.x;
    k3v.y = g.y * invf - qj.y + c0; al += fabsf(k3v.y); as += k3v.y;
    k3v.z = g.z * invf - qj.z + c0; al += fabsf(k3v.z); as += k3v.z;
    k3v.w = g.w * invf - qj.w + c0; al += fabsf(k3v.w); as += k3v.w;
    *(float4*)&row[j0] = k3v;
  }
  red1[t] = al; red2[t] = as;
  __syncthreads();
  for (int sz = 128; sz > 0; sz >>= 1) {
    if (t < sz) { red1[t] += red1[t + sz]; red2[t] += red2[t + sz]; }
    __syncthreads();
  }
  float l1v = red1[0], s3v = red2[0];
  __syncthreads();                 // all threads have l1v/s3v before red1 reuse

  float inv_l1 = 1.0f / (l1v + EPSF);
  float sden = s3v * inv_l1 + 0.01f;
  float inv_s = 1.0f / (sden + EPSF);
  int k0 = kidx[0], k1 = kidx[1], k2 = kidx[2], k3i = kidx[3];
  int k4 = kidx[4], k5 = kidx[5], k6 = kidx[6], k7 = kidx[7];
  bool selfin = (k0 == i) | (k1 == i) | (k2 == i) | (k3i == i) |
                (k4 == i) | (k5 == i) | (k6 == i) | (k7 == i);
  float halfA1 = 0.5f / ((selfin ? 8.0f : 9.0f) + EPSF);

  // sweep 2: A = 0.5*A1 + 0.5*A2 into LDS, accumulate row L1
  float acc = 0.f;
  for (int it = 0; it < N / 1024; ++it) {
    int j0 = it * 1024 + t * 4;
    float4 kv = *(const float4*)&row[j0];
    float4 a;
    {
      int j = j0 + 0;
      float a2 = (kv.x * inv_l1 + ((j == i) ? 0.01f : 0.f)) * inv_s;
      bool mem = (j == i) | (j == k0) | (j == k1) | (j == k2) | (j == k3i) |
                 (j == k4) | (j == k5) | (j == k6) | (j == k7);
      a.x = (mem ? halfA1 : 0.f) + 0.5f * a2;
    }
    {
      int j = j0 + 1;
      float a2 = (kv.y * inv_l1 + ((j == i) ? 0.01f : 0.f)) * inv_s;
      bool mem = (j == i) | (j == k0) | (j == k1) | (j == k2) | (j == k3i) |
                 (j == k4) | (j == k5) | (j == k6) | (j == k7);
      a.y = (mem ? halfA1 : 0.f) + 0.5f * a2;
    }
    {
      int j = j0 + 2;
      float a2 = (kv.z * inv_l1 + ((j == i) ? 0.01f : 0.f)) * inv_s;
      bool mem = (j == i) | (j == k0) | (j == k1) | (j == k2) | (j == k3i) |
                 (j == k4) | (j == k5) | (j == k6) | (j == k7);
      a.z = (mem ? halfA1 : 0.f) + 0.5f * a2;
    }
    {
      int j = j0 + 3;
      float a2 = (kv.w * inv_l1 + ((j == i) ? 0.01f : 0.f)) * inv_s;
      bool mem = (j == i) | (j == k0) | (j == k1) | (j == k2) | (j == k3i) |
                 (j == k4) | (j == k5) | (j == k6) | (j == k7);
      a.w = (mem ? halfA1 : 0.f) + 0.5f * a2;
    }
    *(float4*)&row[j0] = a;
    acc += fabsf(a.x) + fabsf(a.y) + fabsf(a.z) + fabsf(a.w);
  }
  red1[t] = acc;
  __syncthreads();
  for (int sz = 128; sz > 0; sz >>= 1) {
    if (t < sz) red1[t] += red1[t + sz];
    __syncthreads();
  }
  float inv = 1.0f / fmaxf(red1[0], 1e-12f);
  for (int it = 0; it < N / 1024; ++it) {
    int j0 = it * 1024 + t * 4;
    float4 a = *(const float4*)&row[j0];
    a.x *= inv; a.y *= inv; a.z *= inv; a.w *= inv;
    *(float4*)&Gr[j0] = a;
  }
}

// ---------------- launcher ----------------
extern "C" void kernel_launch(void* const* d_in, const int* in_sizes, int n_in,
                              void* d_out, int out_size, void* d_ws, size_t ws_size,
                              hipStream_t stream) {
  const float* x = (const float*)d_in[0];
  float* G = (float*)d_out;        // G lives in d_out, overwritten in place by final A
  float* ws = (float*)d_ws;
  float* z    = ws;                         // N*D f32   (16 MB)
  f16*  zhi   = (f16*)(z + (size_t)N * D);  // N*D f16   (8 MB)
  f16*  zlo   = zhi + (size_t)N * D;        // N*D f16   (8 MB)
  float* m    = (float*)(zlo + (size_t)N * D);  // D
  float* sq   = m + D;                      // N (fast keys)
  float* sqnp = sq + N;                     // N (np-pairwise exact)
  float* p    = sqnp + N;                   // N
  float* rs   = p + N;                      // N
  float* fr   = rs + N;                     // N
  float* q    = fr + N;                     // N
  float* scal = q + N;                      // 16
  int*   cand = (int*)(scal + 16);          // N*16
  int*   knn8 = cand + (size_t)N * 16;      // N*8

  hipMemsetAsync(m, 0, D * sizeof(float), stream);
  k_mean_split<<<N * D / 4 / 256, 256, 0, stream>>>(x, z, zhi, zlo);
  k_sqnp<<<N / 256, 256, 0, stream>>>(z, sqnp);
  k_colmean<<<dim3(2, 32), 256, 0, stream>>>(z, m);
  k_mm<<<1, 512, 0, stream>>>(m, scal);
  k_rowstats<<<N / 4, 256, 0, stream>>>(z, m, sq, p);
  k_gemm<<<(N / 128) * (N / 128), 512, 0, stream>>>(zhi, zlo, G);
  k_pass2<<<N / 4, 256, 0, stream>>>(G, sq, p, scal, rs, fr, cand);
  k_refine<<<N / 16, 256, 0, stream>>>(z, sqnp, cand, knn8);
  k_reduce<<<1, 1024, 0, stream>>>(fr, rs, scal);
  k_prepq<<<N / 256, 256, 0, stream>>>(p, rs, scal, q);
  k_pass4<<<N, 256, 0, stream>>>(G, q, scal, knn8);
}